// Round 1
// baseline (481.527 us; speedup 1.0000x reference)
//
#include <hip/hip_runtime.h>
#include <math.h>

// Problem constants (match reference)
#define B_N 4096
#define L_N 1000
#define M_N 16
#define K_N 20
#define NF  48          // 16 filters x {w1, w2, qw_loc}
#define TVALID 981      // L - K + 1

// Workspace layout (float offsets)
#define WS_W    0       // 48*80 = 3840 floats: [0:16)=w1, [16:32)=w2, [32:48)=qw_loc
#define WS_KL2  3840    // 2 * KL sum
#define WS_S    3841    // s = 1/softplus(gen_scale)
#define WS_S1   3842    // accumulator: sum_b (A[b] - sum_m z*g0)
#define WS_ZSUM 3843    // [16] sum_b z[b,m]
#define WS_BSUM 3859    // [16] sum_b (y*clip(log p2) + (1-y)*clip(log(1-p2)))

static __device__ __forceinline__ float softplus_f(float x) {
    // jax.nn.softplus = logaddexp(x, 0) = max(x,0) + log1p(exp(-|x|))
    return fmaxf(x, 0.f) + log1pf(expf(-fabsf(x)));
}

// ---------------- Kernel 1: derive weights, KL, s; zero accumulators ----------------
__global__ void prep_kernel(const float* __restrict__ qw_loc,
                            const float* __restrict__ qw_scale_raw,
                            const float* __restrict__ gen_scale,
                            const float* __restrict__ eps1,
                            const float* __restrict__ eps2,
                            float* __restrict__ wsf) {
    int tid = threadIdx.x;
    double kl = 0.0;
    for (int i = tid; i < M_N * 80; i += 256) {
        float loc = qw_loc[i];
        float raw = qw_scale_raw[i];
        float qs  = softplus_f(raw);
        wsf[WS_W + i]            = loc + qs * eps1[i];   // w1
        wsf[WS_W + 1280 + i]     = loc + qs * eps2[i];   // w2
        wsf[WS_W + 2560 + i]     = loc;                  // qw_loc
        float dl = loc + 0.01f;  // loc - PRIOR_LOC
        kl += (double)(logf(0.001f / qs) + (qs * qs + dl * dl) / 2e-6f - 0.5f);
    }
    __shared__ double red[256];
    red[tid] = kl;
    __syncthreads();
    for (int s = 128; s > 0; s >>= 1) {
        if (tid < s) red[tid] += red[tid + s];
        __syncthreads();
    }
    if (tid == 0) {
        wsf[WS_KL2] = (float)(2.0 * red[0]);
        wsf[WS_S]   = 1.0f / softplus_f(gen_scale[0]);
        wsf[WS_S1]  = 0.f;
        for (int m = 0; m < M_N; ++m) {
            wsf[WS_ZSUM + m] = 0.f;
            wsf[WS_BSUM + m] = 0.f;
        }
    }
}

// ---------------- Kernel 2: per-sample conv-max for 48 filters + epilogue ----------------
__global__ __launch_bounds__(256) void conv_kernel(const float* __restrict__ x,
                                                   const float* __restrict__ y,
                                                   float* __restrict__ wsf,
                                                   float* __restrict__ out) {
    __shared__ __align__(16) float xs[4][1048];   // 4 x (1024 padded + 24 window) floats
    __shared__ __align__(16) float wsh[NF * 80];
    __shared__ float maxs[NF];

    const int b   = blockIdx.x;
    const int tid = threadIdx.x;

    // Stage x[b] (4 rows of 1000 floats) via float4
    const float4* xg4 = (const float4*)(x + (size_t)b * 4000);
    for (int i = tid; i < 1000; i += 256) {
        float4 v = xg4[i];
        int c = i / 250, off = (i % 250) * 4;
        *(float4*)&xs[c][off] = v;
    }
    if (tid < 192) {  // zero-pad tails (scores there are masked from max)
        int c = tid / 48, p = 1000 + (tid % 48);
        xs[c][p] = 0.f;
    }
    // Stage 48 filters
    const float4* wg4 = (const float4*)(wsf + WS_W);
    for (int i = tid; i < 960; i += 256) ((float4*)wsh)[i] = wg4[i];
    __syncthreads();

    const int wave = tid >> 6, lane = tid & 63;
    const int mbase = wave * 12;   // each wave owns 12 filters over all positions

    float vmax[12];
#pragma unroll
    for (int f = 0; f < 12; ++f) vmax[f] = -INFINITY;

    for (int p = 0; p < 4; ++p) {
        const int t0 = (p * 64 + lane) * 4;     // 4 consecutive positions per lane
        float acc[12][4];
#pragma unroll
        for (int f = 0; f < 12; ++f)
#pragma unroll
            for (int j = 0; j < 4; ++j) acc[f][j] = 0.f;

        for (int c = 0; c < 4; ++c) {
            float win[24];
#pragma unroll
            for (int q = 0; q < 6; ++q) {
                float4 v = *(const float4*)&xs[c][t0 + q * 4];
                win[q * 4 + 0] = v.x; win[q * 4 + 1] = v.y;
                win[q * 4 + 2] = v.z; win[q * 4 + 3] = v.w;
            }
#pragma unroll
            for (int f = 0; f < 12; ++f) {
                const float* wp = &wsh[(mbase + f) * 80 + c * 20];
#pragma unroll
                for (int k4 = 0; k4 < 5; ++k4) {
                    float4 wv = *(const float4*)(wp + k4 * 4);
#define STEP(KK, WC)                                            \
                    acc[f][0] = fmaf(win[(KK) + 0], WC, acc[f][0]); \
                    acc[f][1] = fmaf(win[(KK) + 1], WC, acc[f][1]); \
                    acc[f][2] = fmaf(win[(KK) + 2], WC, acc[f][2]); \
                    acc[f][3] = fmaf(win[(KK) + 3], WC, acc[f][3]);
                    STEP(k4 * 4 + 0, wv.x)
                    STEP(k4 * 4 + 1, wv.y)
                    STEP(k4 * 4 + 2, wv.z)
                    STEP(k4 * 4 + 3, wv.w)
#undef STEP
                }
            }
        }
#pragma unroll
        for (int f = 0; f < 12; ++f)
#pragma unroll
            for (int j = 0; j < 4; ++j)
                if (t0 + j < TVALID) vmax[f] = fmaxf(vmax[f], acc[f][j]);
    }

    // wave-level max reduction (wave owns the filter entirely)
#pragma unroll
    for (int f = 0; f < 12; ++f) {
        float v = vmax[f];
        for (int off = 32; off > 0; off >>= 1)
            v = fmaxf(v, __shfl_xor(v, off, 64));
        if (lane == 0) maxs[mbase + f] = v;
    }
    __syncthreads();

    // ---- epilogue: 16 lanes, one per motif ----
    if (tid < 16) {
        const int m = tid;
        const float s_ = wsf[WS_S];
        const float yb = y[b];
        const float sc1 = maxs[m], sc2 = maxs[16 + m], sc0 = maxs[32 + m];

        // z from w1 scores
        float p1 = 1.f / (1.f + expf(-sc1));
        float lp = logf(p1) + log1pf(-p1);
        float mx = lp;
#pragma unroll
        for (int o = 8; o; o >>= 1) mx = fmaxf(mx, __shfl_xor(mx, o, 16));
        float e = expf(lp - mx);
        float se = e;
#pragma unroll
        for (int o = 8; o; o >>= 1) se += __shfl_xor(se, o, 16);
        float z = e / se;
        float Aterm = z * logf(1e-20f + z);

        // generative term from w2 scores
        float p2 = 1.f / (1.f + expf(-sc2));
        float g0 = -logf(1e-16f + powf(1e-16f + p2, s_) + powf(1.0f - p2, s_));
        float Cterm = z * g0;
        // BCE pieces (reference uses plain log(1-p), clamped at -100)
        float bterm = yb * fmaxf(logf(p2), -100.f)
                    + (1.f - yb) * fmaxf(logf(1.f - p2), -100.f);

        float AC = Aterm - Cterm;
#pragma unroll
        for (int o = 8; o; o >>= 1) AC += __shfl_xor(AC, o, 16);

        atomicAdd(&wsf[WS_ZSUM + m], z);
        atomicAdd(&wsf[WS_BSUM + m], bterm);

        // predict: argmax_m of lp0 (softmax is monotone), first-index ties
        float p0 = 1.f / (1.f + expf(-sc0));
        float lp0 = logf(p0) + log1pf(-p0);
        float best = lp0; int bidx = m;
#pragma unroll
        for (int o = 8; o; o >>= 1) {
            float ov = __shfl_xor(best, o, 16);
            int   oi = __shfl_xor(bidx, o, 16);
            if (ov > best || (ov == best && oi < bidx)) { best = ov; bidx = oi; }
        }
        if (m == 0) {
            atomicAdd(&wsf[WS_S1], AC);
            out[1 + b] = 1.f / (1.f + expf(-maxs[32 + bidx]));
        }
    }
}

// ---------------- Kernel 3: assemble loss ----------------
__global__ void finish_kernel(const float* __restrict__ wsf, float* __restrict__ out) {
    int tid = threadIdx.x;
    if (tid < 16) {
        float t = wsf[WS_ZSUM + tid] * wsf[WS_BSUM + tid];
#pragma unroll
        for (int o = 8; o; o >>= 1) t += __shfl_xor(t, o, 16);
        if (tid == 0) {
            float s_ = wsf[WS_S];
            // loss = S1/B + 2KL + s * sum_m (zsum/B)*(-bsum/B)
            float loss = wsf[WS_S1] / 4096.0f + wsf[WS_KL2]
                       - s_ * (t / (4096.0f * 4096.0f));
            out[0] = loss;
        }
    }
}

extern "C" void kernel_launch(void* const* d_in, const int* in_sizes, int n_in,
                              void* d_out, int out_size, void* d_ws, size_t ws_size,
                              hipStream_t stream) {
    const float* x            = (const float*)d_in[0];
    const float* y            = (const float*)d_in[1];
    const float* qw_loc       = (const float*)d_in[2];
    const float* qw_scale_raw = (const float*)d_in[3];
    const float* gen_scale    = (const float*)d_in[4];
    const float* eps1         = (const float*)d_in[5];
    const float* eps2         = (const float*)d_in[6];
    float* out = (float*)d_out;
    float* wsf = (float*)d_ws;

    prep_kernel<<<1, 256, 0, stream>>>(qw_loc, qw_scale_raw, gen_scale, eps1, eps2, wsf);
    conv_kernel<<<B_N, 256, 0, stream>>>(x, y, wsf, out);
    finish_kernel<<<1, 64, 0, stream>>>(wsf, out);
}